// Round 5
// baseline (595.919 us; speedup 1.0000x reference)
//
#include <hip/hip_runtime.h>
#include <cstdint>
#include <cstddef>

#define GK0 0.7978845608028654f
#define GC1 0.044715f

typedef __attribute__((ext_vector_type(8))) short short8;
typedef __attribute__((ext_vector_type(4))) float floatx4;

__device__ __forceinline__ unsigned short f2bf(float f) {
  union { float f; unsigned int u; } v; v.f = f;
  unsigned int r = v.u + 0x7fffu + ((v.u >> 16) & 1u);   // RNE
  return (unsigned short)(r >> 16);
}

// ---- weights: [co][ci][3][3] f32 -> wt[khw][co][ci] bf16; also zero out ----
__global__ void k_wt(const float* __restrict__ w, unsigned short* __restrict__ wt,
                     float* __restrict__ out) {
  if (blockIdx.x == 0) {
    for (int i = threadIdx.x; i < 32 * 128; i += 256) out[i] = 0.0f;
  }
  int t = blockIdx.x * 256 + threadIdx.x;
  if (t >= 128 * 64 * 9) return;
  int co = t / 576; int r = t - co * 576; int ci = r / 9; int khw = r - ci * 9;
  wt[(khw * 128 + co) * 64 + ci] = f2bf(w[t]);
}

// ---- fused conv + bias + gelu + pool: h-sweep ring pipeline ----
// grid (16 h-groups, 32 b), block 256 (4 waves: wm=co-half x wn=w-half).
// Tile = 1 output row (M=128co x N=128w, K=576). Block sweeps 8 rows; 4-slot
// LDS ring (16KB/row, XOR-swizzled) staged via 32-reg prefetch issued at tile
// start, written to the free slot after the K-loop. Input rows staged ONCE.
__global__ __launch_bounds__(256, 2) void k_conv(
    const float* __restrict__ x, const unsigned short* __restrict__ wt,
    const float* __restrict__ bias, float* __restrict__ out) {
  __shared__ __align__(16) unsigned short xs[4 * 8192];   // 64 KB: 4 row-slots
  const int tid = threadIdx.x;
  const int r0 = blockIdx.x * 8, b = blockIdx.y;
  const int L = min(8, 126 - r0);                         // last block: 6 rows
  const int lane = tid & 63, wave = tid >> 6;
  const int wm = wave & 1, wn = wave >> 1;                // co-half, w-half
  const int m = lane & 15, q = lane >> 4;
  const float* xb32 = x + (size_t)b * 64 * 16384;         // [ci][h][w] fp32
  const int wsp = tid & 127, oh = tid >> 7;               // staging: w, ci-half

  // LDS slot layout (16KB): elem(w,ci) at short-offset w*64 + ((ci>>3 ^ (w&7))<<3) + (ci&7)
  // -> b128 frag reads AND b128 staging writes are uniformly bank-distributed.

  // ---- initial stage: rows r0..r0+2 -> slots 0..2 ----
  for (int rr = 0; rr < 3; rr++) {
    const float* src = xb32 + (size_t)(r0 + rr) * 128 + wsp;
    float pf[32];
#pragma unroll
    for (int g = 0; g < 4; g++)
#pragma unroll
      for (int j = 0; j < 8; j++)
        pf[g * 8 + j] = src[(size_t)((oh * 4 + g) * 8 + j) * 16384];  // coalesced over w
#pragma unroll
    for (int g = 0; g < 4; g++) {
      const int oct = oh * 4 + g;
      short8 sv;
#pragma unroll
      for (int j = 0; j < 8; j++) sv[j] = (short)f2bf(pf[g * 8 + j]);
      *(short8*)&xs[rr * 8192 + wsp * 64 + ((oct ^ (wsp & 7)) << 3)] = sv;
    }
  }
  __syncthreads();

  float bvv[4][4];
#pragma unroll
  for (int mt = 0; mt < 4; mt++)
#pragma unroll
    for (int r2 = 0; r2 < 4; r2++) bvv[mt][r2] = bias[wm * 64 + mt * 16 + q * 4 + r2];

  const unsigned short* wbase = wt + ((wm * 64 + m) * 64 + q * 8);
  float gsum[4][4];
#pragma unroll
  for (int i = 0; i < 4; i++)
#pragma unroll
    for (int j = 0; j < 4; j++) gsum[i][j] = 0.f;

  for (int t = 0; t < L; t++) {
    // issue prefetch of input row r0+t+3 (32 scalar fp32 regs, coalesced)
    const bool pre = (t < L - 1);                  // rows r0..r0+L+1 staged total
    float pf[32];
    if (pre) {
      const float* src = xb32 + (size_t)(r0 + t + 3) * 128 + wsp;
#pragma unroll
      for (int g = 0; g < 4; g++)
#pragma unroll
        for (int j = 0; j < 8; j++)
          pf[g * 8 + j] = src[(size_t)((oh * 4 + g) * 8 + j) * 16384];
    }

    floatx4 acc[4][4];
#pragma unroll
    for (int i = 0; i < 4; i++)
#pragma unroll
      for (int j = 0; j < 4; j++) acc[i][j] = (floatx4){0.f, 0.f, 0.f, 0.f};

    short8 a_cur[4], a_nxt[4];
#pragma unroll
    for (int mt = 0; mt < 4; mt++) a_cur[mt] = *(const short8*)(wbase + mt * 1024);

    const int sbs[3] = {(t & 3) * 8192, ((t + 1) & 3) * 8192, ((t + 2) & 3) * 8192};

#pragma unroll
    for (int kk = 0; kk < 18; kk++) {
      const int khw = kk >> 1, half = kk & 1;
      const int kh = khw / 3, kw = khw - kh * 3;
      if (kk < 17) {   // register double-buffer next A-fragments (L2-resident wt)
        const int khw2 = (kk + 1) >> 1, cb2 = ((kk + 1) & 1) << 5;
        const unsigned short* p = wbase + khw2 * 8192 + cb2;
#pragma unroll
        for (int mt = 0; mt < 4; mt++) a_nxt[mt] = *(const short8*)(p + mt * 1024);
      }
      const int swz = ((q + 4 * half) ^ ((m + kw) & 7)) << 3;
      const int base = sbs[kh] + (wn * 64 + m + kw) * 64 + swz;
      short8 bf[4];
#pragma unroll
      for (int nt = 0; nt < 4; nt++) bf[nt] = *(const short8*)&xs[base + nt * 1024];
#pragma unroll
      for (int mt = 0; mt < 4; mt++)
#pragma unroll
        for (int nt = 0; nt < 4; nt++)
          acc[mt][nt] = __builtin_amdgcn_mfma_f32_16x16x32_bf16(a_cur[mt], bf[nt], acc[mt][nt], 0, 0, 0);
#pragma unroll
      for (int mt = 0; mt < 4; mt++) a_cur[mt] = a_nxt[mt];
    }

    if (pre) {   // convert + write prefetched row into the free slot (t+3)%4
      unsigned short* dst = &xs[((t + 3) & 3) * 8192];
#pragma unroll
      for (int g = 0; g < 4; g++) {
        const int oct = oh * 4 + g;
        short8 sv;
#pragma unroll
        for (int j = 0; j < 8; j++) sv[j] = (short)f2bf(pf[g * 8 + j]);
        *(short8*)&dst[wsp * 64 + ((oct ^ (wsp & 7)) << 3)] = sv;
      }
    }

    // per-tile epilogue: bias + fast tanh-GELU + masked w-sum into gsum
#pragma unroll
    for (int mt = 0; mt < 4; mt++)
#pragma unroll
      for (int r2 = 0; r2 < 4; r2++) {
        float s = 0.f;
#pragma unroll
        for (int nt = 0; nt < 4; nt++) {
          float y = acc[mt][nt][r2] + bvv[mt][r2];
          float u = GK0 * (y + GC1 * y * y * y);
          float e = __expf(-2.0f * u);
          float gg = y * __builtin_amdgcn_rcpf(1.0f + e);  // == 0.5y(1+tanh u)
          if (wn * 64 + nt * 16 + m < 126) s += gg;        // mask w=126,127
        }
        gsum[mt][r2] += s;
      }

    __syncthreads();   // tile t reads done; slot (t)%4 free for tile t+1's write
  }

  // final: reduce gsum over 16 column-lanes, one atomic round per block
  const float inv_area = 1.0f / (126.0f * 126.0f);
  float* orow = out + b * 128;
#pragma unroll
  for (int mt = 0; mt < 4; mt++)
#pragma unroll
    for (int r2 = 0; r2 < 4; r2++) {
      float s = gsum[mt][r2];
#pragma unroll
      for (int d = 1; d < 16; d <<= 1) s += __shfl_xor(s, d, 64);
      if (m == 0) atomicAdd(&orow[wm * 64 + mt * 16 + q * 4 + r2], s * inv_area);
    }
}

extern "C" void kernel_launch(void* const* d_in, const int* in_sizes, int n_in,
                              void* d_out, int out_size, void* d_ws, size_t ws_size,
                              hipStream_t stream) {
  const float* x    = (const float*)d_in[0];
  const float* w    = (const float*)d_in[1];
  const float* bias = (const float*)d_in[2];
  float* out = (float*)d_out;

  unsigned short* wbuf = (unsigned short*)d_ws;   // 9*128*64 bf16 = 144 KiB
  if (ws_size < (size_t)9 * 128 * 64 * 2) return;

  k_wt<<<288, 256, 0, stream>>>(w, wbuf, out);
  k_conv<<<dim3(16, 32), 256, 0, stream>>>(x, wbuf, bias, out);
}

// Round 6
// 380.551 us; speedup vs baseline: 1.5659x; 1.5659x over previous
//
#include <hip/hip_runtime.h>
#include <cstdint>
#include <cstddef>

#define GK0 0.7978845608028654f
#define GC1 0.044715f

typedef __attribute__((ext_vector_type(8))) short short8;
typedef __attribute__((ext_vector_type(4))) float floatx4;

__device__ __forceinline__ unsigned short f2bf(float f) {
  union { float f; unsigned int u; } v; v.f = f;
  unsigned int r = v.u + 0x7fffu + ((v.u >> 16) & 1u);   // RNE
  return (unsigned short)(r >> 16);
}

// async 16B global->LDS (zero VGPR staging; LDS dest = wave-uniform base + lane*16)
__device__ __forceinline__ void gl_lds16(const unsigned short* g, unsigned short* l) {
  __builtin_amdgcn_global_load_lds(
      (const __attribute__((address_space(1))) unsigned int*)g,
      (__attribute__((address_space(3))) unsigned int*)l, 16, 0, 0);
}

// ---- weights: [co][ci][3][3] f32 -> wt[khw][co][ci] bf16; also zero out ----
__global__ void k_wt(const float* __restrict__ w, unsigned short* __restrict__ wt,
                     float* __restrict__ out) {
  if (blockIdx.x == 0) {
    for (int i = threadIdx.x; i < 32 * 128; i += 256) out[i] = 0.0f;
  }
  int t = blockIdx.x * 256 + threadIdx.x;
  if (t >= 128 * 64 * 9) return;
  int co = t / 576; int r = t - co * 576; int ci = r / 9; int khw = r - ci * 9;
  wt[(khw * 128 + co) * 64 + ci] = f2bf(w[t]);
}

// ---- phase 1: NCHW fp32 -> NHWC bf16  xb[b][h][w][ci] ----
// grid (32 h-quads, 32 b), block 256. Coalesced reads (512B runs), LDS fp32
// transpose, coalesced 16B bf16 stores.
__global__ __launch_bounds__(256) void k_xt(const float* __restrict__ x,
                                            unsigned short* __restrict__ xb) {
  __shared__ float tile[64 * 132];                     // pad 132: b128-aligned rows
  const int tid = threadIdx.x, lane = tid & 63, wv = tid >> 6;
  const int b = blockIdx.y, h0 = blockIdx.x * 4;
  const int w4 = lane & 31, cih = lane >> 5;

  for (int r = 0; r < 4; r++) {
    const int h = h0 + r;
#pragma unroll
    for (int j = 0; j < 8; j++) {                      // load 64ci x 128w fp32
      const int ci = wv * 16 + 2 * j + cih;
      float4 f = *(const float4*)(x + ((size_t)(b * 64 + ci) * 128 + h) * 128 + 4 * w4);
      *(float4*)&tile[ci * 132 + 4 * w4] = f;
    }
    __syncthreads();
    unsigned short* orow = xb + ((size_t)b * 128 + h) * 8192;
    const int oct = tid & 7, wlo = tid >> 3;           // wlo in 0..31 across block
#pragma unroll
    for (int it = 0; it < 4; it++) {
      const int w = wlo + 32 * it;
      short8 v;
#pragma unroll
      for (int j = 0; j < 8; j++) v[j] = (short)f2bf(tile[(8 * oct + j) * 132 + w]);
      *(short8*)(orow + w * 64 + oct * 8) = v;         // 16B/lane, contiguous
    }
    __syncthreads();
  }
}

// ---- phase 2: m97-style implicit-GEMM conv + fused bias/GELU/pool ----
// grid (2 w-halves, 63 h-pairs, 32 b), block 256 (4 waves).
// Tile M=128co x N=128pos (2 h-rows x 64 w), K-loop = 9 (kh,kw) steps, BK=64ci.
// Per step: global_load_lds A(16KB wt) + B(16KB xb rows), barrier, 32 MFMA/wave,
// barrier. No VGPR staging -> no spill possible from staging.
__global__ __launch_bounds__(256, 3) void k_conv(
    const unsigned short* __restrict__ xb, const unsigned short* __restrict__ wt,
    const float* __restrict__ bias, float* __restrict__ out) {
  __shared__ __align__(16) unsigned short As[8192];    // [co][ci] 16 KB
  __shared__ __align__(16) unsigned short Bs[8192];    // [n][ci], n = rh*64+w'
  const int tid = threadIdx.x, lane = tid & 63, wv = tid >> 6;
  const int w0 = blockIdx.x * 64, h0 = blockIdx.y * 2, b = blockIdx.z;
  const int wm = wv & 1, wn = wv >> 1;                 // co-half, h-row
  const int m = lane & 15, q = lane >> 4;

  floatx4 acc[4][4];
#pragma unroll
  for (int i = 0; i < 4; i++)
#pragma unroll
    for (int j = 0; j < 4; j++) acc[i][j] = (floatx4){0.f, 0.f, 0.f, 0.f};

  const unsigned short* xbb = xb + (size_t)b * 128 * 8192;
  const int rh = wv >> 1, cc0 = (wv & 1) * 4;          // B-chunk assignment

#pragma unroll
  for (int khw = 0; khw < 9; khw++) {
    const int kh = khw / 3, kw = khw - 3 * kh;
    // stage A: wave wv covers chunks 4wv..4wv+3 (1 KB each)
    const unsigned short* ag = wt + khw * 8192 + wv * 2048 + lane * 8;
    unsigned short* al = As + wv * 2048;
#pragma unroll
    for (int i = 0; i < 4; i++) gl_lds16(ag + i * 512, al + i * 512);
    // stage B: row (h0+rh+kh), w' base w0+kw; contiguous in NHWC
    const unsigned short* bg =
        xbb + ((size_t)(h0 + rh + kh) * 128 + w0 + kw) * 64 + cc0 * 512 + lane * 8;
    unsigned short* bl = Bs + (rh * 8 + cc0) * 512;
#pragma unroll
    for (int i = 0; i < 4; i++) gl_lds16(bg + i * 512, bl + i * 512);
    __syncthreads();                                    // drains vmcnt, then barrier

#pragma unroll
    for (int half = 0; half < 2; half++) {
      short8 a[4], bf[4];
#pragma unroll
      for (int mt = 0; mt < 4; mt++)
        a[mt] = *(const short8*)&As[(wm * 64 + mt * 16 + m) * 64 + half * 32 + q * 8];
#pragma unroll
      for (int nt = 0; nt < 4; nt++)
        bf[nt] = *(const short8*)&Bs[(wn * 64 + nt * 16 + m) * 64 + half * 32 + q * 8];
#pragma unroll
      for (int mt = 0; mt < 4; mt++)
#pragma unroll
        for (int nt = 0; nt < 4; nt++)
          acc[mt][nt] = __builtin_amdgcn_mfma_f32_16x16x32_bf16(a[mt], bf[nt], acc[mt][nt], 0, 0, 0);
    }
    __syncthreads();                                    // LDS reuse for next step
  }

  // epilogue: bias + fast tanh-GELU (y*sigmoid(2u)) + masked pool
  // D layout: col n = wn*64 + nt*16 + (lane&15) -> w' = nt*16+m; row co = q*4+r
  const float inv_area = 1.0f / (126.0f * 126.0f);
  float* orow = out + b * 128;
#pragma unroll
  for (int mt = 0; mt < 4; mt++)
#pragma unroll
    for (int r2 = 0; r2 < 4; r2++) {
      const int co = wm * 64 + mt * 16 + q * 4 + r2;
      const float bv = bias[co];
      float s = 0.f;
#pragma unroll
      for (int nt = 0; nt < 4; nt++) {
        float y = acc[mt][nt][r2] + bv;
        float u = GK0 * (y + GC1 * y * y * y);
        float e = __expf(-2.0f * u);
        float g = y * __builtin_amdgcn_rcpf(1.0f + e);  // == 0.5y(1+tanh u)
        if (w0 + nt * 16 + m < 126) s += g;             // mask padded w' = 126,127
      }
#pragma unroll
      for (int d = 1; d < 16; d <<= 1) s += __shfl_xor(s, d, 64);
      if (m == 0) atomicAdd(&orow[co], s * inv_area);
    }
}

extern "C" void kernel_launch(void* const* d_in, const int* in_sizes, int n_in,
                              void* d_out, int out_size, void* d_ws, size_t ws_size,
                              hipStream_t stream) {
  const float* x    = (const float*)d_in[0];
  const float* w    = (const float*)d_in[1];
  const float* bias = (const float*)d_in[2];
  float* out = (float*)d_out;

  const size_t xb_elems = (size_t)32 * 128 * 8192;      // 64 MiB bf16 NHWC
  unsigned short* xbuf = (unsigned short*)d_ws;
  unsigned short* wbuf = xbuf + xb_elems + 2048;        // 4 KB slack (B halo overreads)
  if (ws_size < xb_elems * 2 + 4096 + (size_t)9 * 128 * 64 * 2) return;

  k_wt<<<288, 256, 0, stream>>>(w, wbuf, out);
  k_xt<<<dim3(32, 32), 256, 0, stream>>>(x, xbuf);
  k_conv<<<dim3(2, 63, 32), 256, 0, stream>>>(xbuf, wbuf, bias, out);
}